// Round 8
// baseline (424.168 us; speedup 1.0000x reference)
//
#include <hip/hip_runtime.h>

// Problem constants (B,C,H,W fixed by setup_inputs)
#define BB  16
#define HH  384
#define WW  1280
#define TPB 320   // 5 waves; thread t owns cols 4t..4t+3 => whole 1280-col row/block
#define ROWS 12   // 384 = 32*12 strips; grid 32x16 = 512 blocks = 2 blocks/CU
#define NSLOT 64  // accumulator slots, one 64B line each

__device__ __forceinline__ float getc(const float4& v, int k) {
    return k == 0 ? v.x : k == 1 ? v.y : k == 2 ? v.z : v.w;
}

// Consume a raw row (q = 4 owned cols, E = this lane's edge value if lane 0/63)
// into horizontal diff D and 3-sum T, using wave shuffles for neighbors.
__device__ __forceinline__ void dt4(const float4 q, float E, bool eok,
                                    bool is_l, bool is_r, float4& D, float4& T) {
    float el = __shfl_up(q.w, 1);    // lane-1's col0+3  == our col0-1
    float er = __shfl_down(q.x, 1);  // lane+1's col0    == our col0+4
    float Ev = eok ? E : 0.f;        // edge lanes: loaded value or zero-pad
    el = is_l ? Ev : el;
    er = is_r ? Ev : er;
    D.x = q.y - el;   D.y = q.z - q.x;  D.z = q.w - q.y;  D.w = er - q.z;
    T.x = el + q.x + q.y;  T.y = q.x + q.y + q.z;
    T.z = q.y + q.z + q.w; T.w = q.z + q.w + er;
}

__global__ __launch_bounds__(TPB)   // no min-waves arg: R3 showed it forces spills
void NormalLoss_44478681317469_main(const float* __restrict__ pred,
                                    const float* __restrict__ gt,
                                    const float* __restrict__ mask,
                                    double* __restrict__ acc)
{
    const int t    = threadIdx.x;          // 0..319
    const int lane = t & 63;
    const int col0 = t * 4;                // 0..1276
    const int r0   = blockIdx.x * ROWS;
    const int b    = blockIdx.y;

    const float* pl[6];
#pragma unroll
    for (int c = 0; c < 3; ++c) {
        pl[c]     = pred + (size_t)(b * 3 + c) * HH * WW;
        pl[3 + c] = gt   + (size_t)(b * 3 + c) * HH * WW;
    }
    const float* mpl = mask + (size_t)b * HH * WW;

    // Edge-lane bookkeeping: lanes 0/63 fetch the one neighbor dword their
    // shfl can't see (previous/next wave's segment). Address always valid.
    const bool has_l = (col0 > 0);
    const bool has_r = (col0 + 4 < WW);
    const bool is_l  = (lane == 0);
    const bool is_r  = (lane == 63);
    const bool edge  = is_l || is_r;
    const int  jedge = is_l ? (has_l ? col0 - 1 : 0) : (has_r ? col0 + 4 : 0);
    const bool eok   = is_l ? has_l : has_r;

    // Rolling D/T state rows i-1, i (float4 per plane) + raw lookahead row i+1.
    float4 Dm1[6], D0[6], Tm1[6], T0[6], Q[6];
    float  E[6];
    float4 mrow;

    // ---- prologue
#pragma unroll
    for (int c = 0; c < 6; ++c) {
        E[c] = 0.f;
        if (r0 > 0) {   // uniform per block
            const int rb = (r0 - 1) * WW;
            float4 q = *(const float4*)(pl[c] + rb + col0);
            float  e = edge ? pl[c][rb + jedge] : 0.f;
            dt4(q, e, eok, is_l, is_r, Dm1[c], Tm1[c]);
        } else {
            Dm1[c] = make_float4(0.f, 0.f, 0.f, 0.f);
            Tm1[c] = make_float4(0.f, 0.f, 0.f, 0.f);
        }
        {
            const int rb = r0 * WW;
            float4 q = *(const float4*)(pl[c] + rb + col0);
            float  e = edge ? pl[c][rb + jedge] : 0.f;
            dt4(q, e, eok, is_l, is_r, D0[c], T0[c]);
        }
    }
    {   // prefetch row r0+1 (r0+1 <= 373 < HH always)
        const int rb = (r0 + 1) * WW;
#pragma unroll
        for (int c = 0; c < 6; ++c) {
            Q[c] = *(const float4*)(pl[c] + rb + col0);
            if (edge) E[c] = pl[c][rb + jedge];
        }
    }
    mrow = *(const float4*)(mpl + (size_t)r0 * WW + col0);

    float lsum = 0.f, msum = 0.f;

#pragma unroll 2    // rolling loop: compact VGPR allocation (R5 lesson)
    for (int k = 0; k < ROWS; ++k) {
        const int i = r0 + k;

        // Consume lookahead plane-by-plane; rotate immediately so Dp/Tp die fast.
        float4 gx[6], gy[6];
#pragma unroll
        for (int c = 0; c < 6; ++c) {
            float4 Dp, Tp;
            dt4(Q[c], E[c], eok, is_l, is_r, Dp, Tp);
            gx[c].x = Dm1[c].x + D0[c].x + Dp.x;
            gx[c].y = Dm1[c].y + D0[c].y + Dp.y;
            gx[c].z = Dm1[c].z + D0[c].z + Dp.z;
            gx[c].w = Dm1[c].w + D0[c].w + Dp.w;
            gy[c].x = Tp.x - Tm1[c].x;
            gy[c].y = Tp.y - Tm1[c].y;
            gy[c].z = Tp.z - Tm1[c].z;
            gy[c].w = Tp.w - Tm1[c].w;
            Dm1[c] = D0[c]; D0[c] = Dp;
            Tm1[c] = T0[c]; T0[c] = Tp;
        }
        const float4 m = mrow;

        // Prefetch row i+2 (+ next mask row) NOW; in flight during math below.
        if (i + 2 < HH) {   // uniform per block
            const int rb = (i + 2) * WW;
#pragma unroll
            for (int c = 0; c < 6; ++c) {
                Q[c] = *(const float4*)(pl[c] + rb + col0);
                if (edge) E[c] = pl[c][rb + jedge];
            }
        } else {
#pragma unroll
            for (int c = 0; c < 6; ++c) {
                Q[c] = make_float4(0.f, 0.f, 0.f, 0.f); E[c] = 0.f;
            }
        }
        if (k + 1 < ROWS) mrow = *(const float4*)(mpl + (size_t)(i + 1) * WW + col0);

        // Math for the 4 owned pixels (factor 3 dropped; cancels in normalize).
#pragma unroll
        for (int p = 0; p < 4; ++p) {
            float gx0 = getc(gx[0], p), gx1 = getc(gx[1], p), gx2 = getc(gx[2], p);
            float gy0 = getc(gy[0], p), gy1 = getc(gy[1], p), gy2 = getc(gy[2], p);
            float hx0 = getc(gx[3], p), hx1 = getc(gx[4], p), hx2 = getc(gx[5], p);
            float hy0 = getc(gy[3], p), hy1 = getc(gy[4], p), hy2 = getc(gy[5], p);

            float n0p = gx1 * gy2 - gx2 * gy1;
            float n1p = gx2 * gy0 - gx0 * gy2;
            float n2p = gx0 * gy1 - gx1 * gy0;
            float n0g = hx1 * hy2 - hx2 * hy1;
            float n1g = hx2 * hy0 - hx0 * hy2;
            float n2g = hx0 * hy1 - hx1 * hy0;

            float sp = n0p * n0p + n1p * n1p + n2p * n2p;
            float sg = n0g * n0g + n1g * n1g + n2g * n2g;
            // ref: normal/(sqrt(s)+1e-10); rsq rel-err ~2e-6; guard s~0 -> 0
            float ip = (sp > 1e-20f) ? __builtin_amdgcn_rsqf(sp) : 0.f;
            float ig = (sg > 1e-20f) ? __builtin_amdgcn_rsqf(sg) : 0.f;

            float d0 = fabsf(n0p * ip - n0g * ig);
            float d1 = fabsf(n1p * ip - n1g * ig);
            float d2 = fabsf(n2p * ip - n2g * ig);

            float mv = getc(m, p);
            lsum += mv * (d0 + d1 + d2);
            msum += mv;
        }
    }

    // Wave(64) shuffle reduction, cross-wave via LDS, one atomic pair per block.
#pragma unroll
    for (int off = 32; off > 0; off >>= 1) {
        lsum += __shfl_down(lsum, off, 64);
        msum += __shfl_down(msum, off, 64);
    }
    __shared__ float sL[TPB / 64], sM[TPB / 64];
    const int wid = t >> 6;
    if (lane == 0) { sL[wid] = lsum; sM[wid] = msum; }
    __syncthreads();
    if (t == 0) {
        float L = 0.f, M = 0.f;
#pragma unroll
        for (int w = 0; w < TPB / 64; ++w) { L += sL[w]; M += sM[w]; }
        const int linear = blockIdx.y * gridDim.x + blockIdx.x;
        double* slot = acc + (size_t)(linear & (NSLOT - 1)) * 8;  // 64B stride
        atomicAdd(&slot[0], (double)L);
        atomicAdd(&slot[1], (double)M);
    }
}

__global__ void NormalLoss_44478681317469_final(const double* __restrict__ acc,
                                                float* __restrict__ out)
{
    const int t = threadIdx.x;   // 64 threads, one per slot
    double L = acc[(size_t)t * 8 + 0];
    double M = acc[(size_t)t * 8 + 1];
#pragma unroll
    for (int off = 32; off > 0; off >>= 1) {
        L += __shfl_down(L, off, 64);
        M += __shfl_down(M, off, 64);
    }
    if (t == 0) out[0] = (float)(L / M);
}

extern "C" void kernel_launch(void* const* d_in, const int* in_sizes, int n_in,
                              void* d_out, int out_size, void* d_ws, size_t ws_size,
                              hipStream_t stream)
{
    const float* pred = (const float*)d_in[0];
    const float* gt   = (const float*)d_in[1];
    const float* mask = (const float*)d_in[2];
    double* acc = (double*)d_ws;

    // d_ws is poisoned 0xAA before every timed launch — zero the slot array.
    hipMemsetAsync(acc, 0, NSLOT * 8 * sizeof(double), stream);

    dim3 grid(HH / ROWS, BB);   // 32 x 16 = 512 blocks, 5 waves each
    NormalLoss_44478681317469_main<<<grid, dim3(TPB), 0, stream>>>(pred, gt, mask, acc);
    NormalLoss_44478681317469_final<<<1, 64, 0, stream>>>(acc, (float*)d_out);
}

// Round 9
// 238.824 us; speedup vs baseline: 1.7761x; 1.7761x over previous
//
#include <hip/hip_runtime.h>

// Problem constants (B,C,H,W fixed by setup_inputs)
#define BB  16
#define HH  384
#define WW  1280
#define TPB 256   // threads per block, along W (1280 = 5*256)
#define ROWS 16   // rows per strip (384 = 24*16); grid 1920 blocks (R6 shape)
#define NSLOT 64  // accumulator slots, one 64B line each

// Raw 3-tap row fetch with column zero-padding.
__device__ __forceinline__ void load_row3(const float* __restrict__ plane, int i, int j,
                                          float& a, float& b, float& c) {
    const float* row = plane + (size_t)i * WW;
    a = (j > 0)      ? row[j - 1] : 0.f;
    b = row[j];
    c = (j < WW - 1) ? row[j + 1] : 0.f;
}

// One pipeline step at row i = r0+k. Consumes lookahead group (A,B,C) holding
// raw row i+1 (issued TWO iterations ago -> ~1000 busy-cycles of latency
// coverage), refills it with row i+3, consumes mask mreg (row i), refills
// with mask row i+2. Updates rolling D/T state and the running sums.
__device__ __forceinline__ void step(
    int k, int r0, int j, const float* const* pl, const float* mpl,
    float (&A)[6], float (&B)[6], float (&C)[6], float& mreg,
    float (&Dm1)[6], float (&D0)[6], float (&Tm1)[6], float (&T0)[6],
    float& lsum, float& msum)
{
    const int i = r0 + k;

    // Consume lookahead -> D/T for row i+1.
    float Dp1[6], Tp1[6];
#pragma unroll
    for (int c = 0; c < 6; ++c) {
        Dp1[c] = C[c] - A[c];
        Tp1[c] = A[c] + B[c] + C[c];
    }
    const float m = mreg;

    // Refill this group with row i+3 (depth-2 lookahead) + mask row i+2.
    if (i + 3 < HH) {   // uniform per block
#pragma unroll
        for (int c = 0; c < 6; ++c) load_row3(pl[c], i + 3, j, A[c], B[c], C[c]);
    } else {
#pragma unroll
        for (int c = 0; c < 6; ++c) { A[c] = 0.f; B[c] = 0.f; C[c] = 0.f; }
    }
    if (k + 2 < ROWS) mreg = mpl[(size_t)(i + 2) * WW + j];   // uniform guard

    // Gradients (global factor 3 dropped; cancels in normalization)
    float gx[6], gy[6];
#pragma unroll
    for (int c = 0; c < 6; ++c) {
        gx[c] = Dm1[c] + D0[c] + Dp1[c];
        gy[c] = Tp1[c] - Tm1[c];
    }

    // normal = cross(gx_vec, gy_vec), per reference component expressions
    float n0p = gx[1] * gy[2] - gx[2] * gy[1];
    float n1p = gx[2] * gy[0] - gx[0] * gy[2];
    float n2p = gx[0] * gy[1] - gx[1] * gy[0];
    float n0g = gx[4] * gy[5] - gx[5] * gy[4];
    float n1g = gx[5] * gy[3] - gx[3] * gy[5];
    float n2g = gx[3] * gy[4] - gx[4] * gy[3];

    float sp = n0p * n0p + n1p * n1p + n2p * n2p;
    float sg = n0g * n0g + n1g * n1g + n2g * n2g;
    // ref: normal/(sqrt(s)+1e-10); rsq rel-err ~2e-6; guard s~0 -> 0
    float ip = (sp > 1e-20f) ? __builtin_amdgcn_rsqf(sp) : 0.f;
    float ig = (sg > 1e-20f) ? __builtin_amdgcn_rsqf(sg) : 0.f;

    float d0 = fabsf(n0p * ip - n0g * ig);
    float d1 = fabsf(n1p * ip - n1g * ig);
    float d2 = fabsf(n2p * ip - n2g * ig);

    lsum += m * (d0 + d1 + d2);
    msum += m;

    // Rotate rolling state.
#pragma unroll
    for (int c = 0; c < 6; ++c) {
        Dm1[c] = D0[c]; D0[c] = Dp1[c];
        Tm1[c] = T0[c]; T0[c] = Tp1[c];
    }
}

__global__ __launch_bounds__(TPB)   // no min-waves arg: R3/R7 showed spills
void NormalLoss_44478681317469_main(const float* __restrict__ pred,
                                    const float* __restrict__ gt,
                                    const float* __restrict__ mask,
                                    double* __restrict__ acc)
{
    const int j  = blockIdx.x * TPB + threadIdx.x;   // column
    const int r0 = blockIdx.y * ROWS;                // strip start row
    const int b  = blockIdx.z;

    const float* pl[6];
#pragma unroll
    for (int c = 0; c < 3; ++c) {
        pl[c]     = pred + (size_t)(b * 3 + c) * HH * WW;
        pl[3 + c] = gt   + (size_t)(b * 3 + c) * HH * WW;
    }
    const float* mpl = mask + (size_t)b * HH * WW;

    // Rolling D (horiz diff) / T (horiz sum) state for rows i-1, i.
    float Dm1[6], D0[6], Tm1[6], T0[6];

#pragma unroll
    for (int c = 0; c < 6; ++c) {
        if (r0 > 0) {   // uniform per block
            float a, bb, cc; load_row3(pl[c], r0 - 1, j, a, bb, cc);
            Dm1[c] = cc - a; Tm1[c] = a + bb + cc;
        } else { Dm1[c] = 0.f; Tm1[c] = 0.f; }   // zero padding above row 0
        {
            float a, bb, cc; load_row3(pl[c], r0, j, a, bb, cc);
            D0[c] = cc - a; T0[c] = a + bb + cc;
        }
    }

    // Two lookahead groups: G0 = row r0+1, G1 = row r0+2 (both always < HH:
    // r0 <= 368 -> r0+2 <= 370 < 384). Masks: m0 = row r0, m1 = row r0+1.
    float A0[6], B0[6], C0[6], A1[6], B1[6], C1[6];
#pragma unroll
    for (int c = 0; c < 6; ++c) load_row3(pl[c], r0 + 1, j, A0[c], B0[c], C0[c]);
    float m0 = mpl[(size_t)r0 * WW + j];
#pragma unroll
    for (int c = 0; c < 6; ++c) load_row3(pl[c], r0 + 2, j, A1[c], B1[c], C1[c]);
    float m1 = mpl[(size_t)(r0 + 1) * WW + j];

    float lsum = 0.f, msum = 0.f;

    // Manual unroll-by-2: groups alternate, no lookahead-register rotation.
    for (int k = 0; k < ROWS; k += 2) {
        step(k,     r0, j, pl, mpl, A0, B0, C0, m0, Dm1, D0, Tm1, T0, lsum, msum);
        step(k + 1, r0, j, pl, mpl, A1, B1, C1, m1, Dm1, D0, Tm1, T0, lsum, msum);
    }

    // Wave(64) shuffle reduction, cross-wave via LDS, one atomic pair per block.
#pragma unroll
    for (int off = 32; off > 0; off >>= 1) {
        lsum += __shfl_down(lsum, off, 64);
        msum += __shfl_down(msum, off, 64);
    }
    __shared__ float sL[TPB / 64], sM[TPB / 64];
    const int lane = threadIdx.x & 63;
    const int wid  = threadIdx.x >> 6;
    if (lane == 0) { sL[wid] = lsum; sM[wid] = msum; }
    __syncthreads();
    if (threadIdx.x == 0) {
        float L = 0.f, M = 0.f;
#pragma unroll
        for (int w = 0; w < TPB / 64; ++w) { L += sL[w]; M += sM[w]; }
        const int linear = (blockIdx.z * gridDim.y + blockIdx.y) * gridDim.x + blockIdx.x;
        double* slot = acc + (size_t)(linear & (NSLOT - 1)) * 8;  // 64B stride
        atomicAdd(&slot[0], (double)L);
        atomicAdd(&slot[1], (double)M);
    }
}

__global__ void NormalLoss_44478681317469_final(const double* __restrict__ acc,
                                                float* __restrict__ out)
{
    const int t = threadIdx.x;   // 64 threads, one per slot
    double L = acc[(size_t)t * 8 + 0];
    double M = acc[(size_t)t * 8 + 1];
#pragma unroll
    for (int off = 32; off > 0; off >>= 1) {
        L += __shfl_down(L, off, 64);
        M += __shfl_down(M, off, 64);
    }
    if (t == 0) out[0] = (float)(L / M);
}

extern "C" void kernel_launch(void* const* d_in, const int* in_sizes, int n_in,
                              void* d_out, int out_size, void* d_ws, size_t ws_size,
                              hipStream_t stream)
{
    const float* pred = (const float*)d_in[0];
    const float* gt   = (const float*)d_in[1];
    const float* mask = (const float*)d_in[2];
    double* acc = (double*)d_ws;

    // d_ws is poisoned 0xAA before every timed launch — zero the slot array.
    hipMemsetAsync(acc, 0, NSLOT * 8 * sizeof(double), stream);

    dim3 grid(WW / TPB, HH / ROWS, BB);   // 5 x 24 x 16 = 1920 blocks
    NormalLoss_44478681317469_main<<<grid, dim3(TPB), 0, stream>>>(pred, gt, mask, acc);
    NormalLoss_44478681317469_final<<<1, 64, 0, stream>>>(acc, (float*)d_out);
}